// Round 1
// baseline (2941.261 us; speedup 1.0000x reference)
//
#include <hip/hip_runtime.h>

#define KTAPS 8
#define C 32

// Fill output with bias (vectorized float4: 32 floats/row = 8 float4/row).
__global__ __launch_bounds__(256) void bias_init_kernel(
    float* __restrict__ out, const float* __restrict__ bias, int n4) {
  int idx = blockIdx.x * 256 + threadIdx.x;
  if (idx >= n4) return;
  const float4* b4 = (const float4*)bias;
  ((float4*)out)[idx] = b4[idx & 7];
}

// One thread = one rule. blockIdx.y = k (tap), so the weight matrix is
// block-uniform -> compiler scalar-loads W[k] (s_load) and every inner
// instruction is v_fmac_f32 v, s, v: 1024 FMAs/rule across 64-lane waves
// = 16 wave-inst/rule, pure FMA.
__global__ __launch_bounds__(256) void scatter_gemm_kernel(
    const float* __restrict__ in, const float* __restrict__ w,
    const int* __restrict__ rules_in, const int* __restrict__ rules_out,
    float* __restrict__ out, int R) {
  const int k = blockIdx.y;
  const int r = blockIdx.x * 256 + threadIdx.x;
  if (r >= R) return;

  const int ri = rules_in[k * R + r];
  const int ro = rules_out[k * R + r];

  // Load this rule's input row (128 B) into registers.
  const float4* rowp = (const float4*)(in + ri * C);
  float a[C];
#pragma unroll
  for (int j = 0; j < 8; ++j) {
    float4 v = rowp[j];
    a[4 * j + 0] = v.x;
    a[4 * j + 1] = v.y;
    a[4 * j + 2] = v.z;
    a[4 * j + 3] = v.w;
  }

  // acc[co] = sum_ci a[ci] * W[k][ci][co]; weight index is uniform.
  const float* wk = w + k * (C * C);
  float acc[C];
#pragma unroll
  for (int co = 0; co < C; ++co) acc[co] = a[0] * wk[co];
#pragma unroll
  for (int ci = 1; ci < C; ++ci) {
#pragma unroll
    for (int co = 0; co < C; ++co)
      acc[co] = fmaf(a[ci], wk[ci * C + co], acc[co]);
  }

  // Scatter-add into the output row (native f32 atomics, device scope).
  float* op = out + ro * C;
#pragma unroll
  for (int co = 0; co < C; ++co) unsafeAtomicAdd(op + co, acc[co]);
}

extern "C" void kernel_launch(void* const* d_in, const int* in_sizes, int n_in,
                              void* d_out, int out_size, void* d_ws, size_t ws_size,
                              hipStream_t stream) {
  const float* in_features = (const float*)d_in[0];
  const float* weight      = (const float*)d_in[1];
  const float* bias        = (const float*)d_in[2];
  const int*   rules_in    = (const int*)d_in[3];
  const int*   rules_out   = (const int*)d_in[4];

  const int R = in_sizes[3] / KTAPS;       // 200000
  float* out = (float*)d_out;

  // 1) out[n][c] = bias[c]
  const int n4 = out_size / 4;             // float4 count (out_size = n_out*32)
  bias_init_kernel<<<(n4 + 255) / 256, 256, 0, stream>>>(out, bias, n4);

  // 2) gather -> 32x32 GEMM -> atomic scatter
  dim3 grid((R + 255) / 256, KTAPS);
  scatter_gemm_kernel<<<grid, 256, 0, stream>>>(in_features, weight, rules_in,
                                                rules_out, out, R);
}

// Round 2
// 925.822 us; speedup vs baseline: 3.1769x; 3.1769x over previous
//
#include <hip/hip_runtime.h>
#include <stdint.h>

#define KTAPS 8
#define C 32
#define CAP 4   // bucket slots per (out_row, tap) cell; Poisson(0.5) => overflow ~1e-4

// ---------------------------------------------------------------------------
// init: out[row][c] = bias[c]  and  counts[cell] = 0  (both are poisoned 0xAA)
// ---------------------------------------------------------------------------
__global__ __launch_bounds__(256) void init_kernel(
    float* __restrict__ out, const float* __restrict__ bias,
    unsigned int* __restrict__ counts, int n_out4, int n_cells4) {
  int i = blockIdx.x * 256 + threadIdx.x;
  if (i < n_out4) {
    ((float4*)out)[i] = ((const float4*)bias)[i & 7];
  }
  if (i < n_cells4) {
    ((uint4*)counts)[i] = make_uint4(0u, 0u, 0u, 0u);
  }
}

// ---------------------------------------------------------------------------
// Phase B: invert the scatter. One thread per (tap, rule): claim a slot in the
// (out_row, tap) bucket with ONE int atomic and store the input-row index.
// Rare overflow (slot >= CAP) computes the contribution inline and adds it
// directly with f32 atomics (correct at any cap).
// ---------------------------------------------------------------------------
__global__ __launch_bounds__(256) void bucket_kernel(
    const float* __restrict__ in, const float* __restrict__ w,
    const int* __restrict__ rules_in, const int* __restrict__ rules_out,
    float* __restrict__ out, unsigned int* __restrict__ counts,
    unsigned int* __restrict__ buckets, int R) {
  const int k = blockIdx.y;
  const int r = blockIdx.x * 256 + threadIdx.x;
  if (r >= R) return;

  const int ri = rules_in[k * R + r];
  const int ro = rules_out[k * R + r];
  const unsigned int cell = (unsigned int)ro * KTAPS + (unsigned int)k;
  const unsigned int slot = atomicAdd(counts + cell, 1u);

  if (slot < (unsigned int)CAP) {
    buckets[(size_t)cell * CAP + slot] = (unsigned int)ri;
  } else {
    // ---- rare overflow path: inline GEMM + direct atomic scatter ----
    const float4* rowp = (const float4*)(in + (size_t)ri * C);
    float a[C];
#pragma unroll
    for (int j = 0; j < 8; ++j) {
      float4 v = rowp[j];
      a[4 * j + 0] = v.x; a[4 * j + 1] = v.y;
      a[4 * j + 2] = v.z; a[4 * j + 3] = v.w;
    }
    const float* wk = w + k * (C * C);
    float acc[C];
#pragma unroll
    for (int co = 0; co < C; ++co) acc[co] = a[0] * wk[co];
#pragma unroll
    for (int ci = 1; ci < C; ++ci)
#pragma unroll
      for (int co = 0; co < C; ++co)
        acc[co] = fmaf(a[ci], wk[ci * C + co], acc[co]);
    float* op = out + (size_t)ro * C;
#pragma unroll
    for (int co = 0; co < C; ++co) unsafeAtomicAdd(op + co, acc[co]);
  }
}

// ---------------------------------------------------------------------------
// Phase C: one thread per output row PULLS its contributions. Tap index k is a
// uniform loop var -> weights are scalar-loaded (v_fmac v, s, v). Row written
// exactly once (on top of bias + any overflow atomics already landed).
// k-loop deliberately NOT unrolled to keep the 1024-FMA body out of icache x8.
// ---------------------------------------------------------------------------
__global__ __launch_bounds__(256) void gather_kernel(
    const float* __restrict__ in, const float* __restrict__ w,
    const unsigned int* __restrict__ counts,
    const unsigned int* __restrict__ buckets,
    float* __restrict__ out, int n_out) {
  const int row = blockIdx.x * 256 + threadIdx.x;
  if (row >= n_out) return;

  float acc[C];
  float4* o4 = (float4*)(out + (size_t)row * C);
#pragma unroll
  for (int j = 0; j < 8; ++j) {
    float4 v = o4[j];
    acc[4 * j + 0] = v.x; acc[4 * j + 1] = v.y;
    acc[4 * j + 2] = v.z; acc[4 * j + 3] = v.w;
  }

  for (int k = 0; k < KTAPS; ++k) {               // uniform, not unrolled
    unsigned int n = counts[(size_t)row * KTAPS + k];
    if (n > (unsigned int)CAP) n = (unsigned int)CAP;
    const float* wk = w + k * (C * C);            // uniform -> s_load weights
    const unsigned int* bk = buckets + ((size_t)row * KTAPS + k) * CAP;
    for (unsigned int e = 0; e < n; ++e) {        // divergent trip count
      unsigned int ri = bk[e];
      const float4* rowp = (const float4*)(in + (size_t)ri * C);
      float a[C];
#pragma unroll
      for (int j = 0; j < 8; ++j) {
        float4 v = rowp[j];
        a[4 * j + 0] = v.x; a[4 * j + 1] = v.y;
        a[4 * j + 2] = v.z; a[4 * j + 3] = v.w;
      }
#pragma unroll
      for (int ci = 0; ci < C; ++ci)
#pragma unroll
        for (int co = 0; co < C; ++co)
          acc[co] = fmaf(a[ci], wk[ci * C + co], acc[co]);
    }
  }

#pragma unroll
  for (int j = 0; j < 8; ++j)
    o4[j] = make_float4(acc[4 * j + 0], acc[4 * j + 1],
                        acc[4 * j + 2], acc[4 * j + 3]);
}

// ---------------------------------------------------------------------------
// Legacy fallback (round-1 kernels) if the workspace is too small.
// ---------------------------------------------------------------------------
__global__ __launch_bounds__(256) void bias_init_kernel(
    float* __restrict__ out, const float* __restrict__ bias, int n4) {
  int idx = blockIdx.x * 256 + threadIdx.x;
  if (idx >= n4) return;
  ((float4*)out)[idx] = ((const float4*)bias)[idx & 7];
}

__global__ __launch_bounds__(256) void scatter_gemm_kernel(
    const float* __restrict__ in, const float* __restrict__ w,
    const int* __restrict__ rules_in, const int* __restrict__ rules_out,
    float* __restrict__ out, int R) {
  const int k = blockIdx.y;
  const int r = blockIdx.x * 256 + threadIdx.x;
  if (r >= R) return;
  const int ri = rules_in[k * R + r];
  const int ro = rules_out[k * R + r];
  const float4* rowp = (const float4*)(in + (size_t)ri * C);
  float a[C];
#pragma unroll
  for (int j = 0; j < 8; ++j) {
    float4 v = rowp[j];
    a[4 * j + 0] = v.x; a[4 * j + 1] = v.y;
    a[4 * j + 2] = v.z; a[4 * j + 3] = v.w;
  }
  const float* wk = w + k * (C * C);
  float acc[C];
#pragma unroll
  for (int co = 0; co < C; ++co) acc[co] = a[0] * wk[co];
#pragma unroll
  for (int ci = 1; ci < C; ++ci)
#pragma unroll
    for (int co = 0; co < C; ++co)
      acc[co] = fmaf(a[ci], wk[ci * C + co], acc[co]);
  float* op = out + (size_t)ro * C;
#pragma unroll
  for (int co = 0; co < C; ++co) unsafeAtomicAdd(op + co, acc[co]);
}

extern "C" void kernel_launch(void* const* d_in, const int* in_sizes, int n_in,
                              void* d_out, int out_size, void* d_ws, size_t ws_size,
                              hipStream_t stream) {
  const float* in_features = (const float*)d_in[0];
  const float* weight      = (const float*)d_in[1];
  const float* bias        = (const float*)d_in[2];
  const int*   rules_in    = (const int*)d_in[3];
  const int*   rules_out   = (const int*)d_in[4];

  const int R     = in_sizes[3] / KTAPS;   // 200000
  const int n_out = out_size / C;          // 400000
  float* out = (float*)d_out;

  const size_t n_cells     = (size_t)n_out * KTAPS;          // 3.2M
  const size_t counts_b    = n_cells * sizeof(unsigned int); // 12.8 MB
  const size_t buckets_b   = n_cells * CAP * sizeof(unsigned int); // 51.2 MB
  const size_t need        = counts_b + buckets_b;           // 64 MB

  if (ws_size >= need) {
    unsigned int* counts  = (unsigned int*)d_ws;
    unsigned int* buckets = (unsigned int*)((char*)d_ws + counts_b);

    const int n_out4   = out_size / 4;           // 3.2M float4
    const int n_cells4 = (int)(n_cells / 4);     // 800K uint4
    int init_n = n_out4 > n_cells4 ? n_out4 : n_cells4;
    init_kernel<<<(init_n + 255) / 256, 256, 0, stream>>>(out, bias, counts,
                                                          n_out4, n_cells4);

    dim3 gridB((R + 255) / 256, KTAPS);
    bucket_kernel<<<gridB, 256, 0, stream>>>(in_features, weight, rules_in,
                                             rules_out, out, counts, buckets, R);

    gather_kernel<<<(n_out + 255) / 256, 256, 0, stream>>>(
        in_features, weight, counts, buckets, out, n_out);
  } else {
    // workspace too small: correct-but-slow atomic path
    const int n4 = out_size / 4;
    bias_init_kernel<<<(n4 + 255) / 256, 256, 0, stream>>>(out, bias, n4);
    dim3 grid((R + 255) / 256, KTAPS);
    scatter_gemm_kernel<<<grid, 256, 0, stream>>>(in_features, weight, rules_in,
                                                  rules_out, out, R);
  }
}

// Round 3
// 583.076 us; speedup vs baseline: 5.0444x; 1.5878x over previous
//
#include <hip/hip_runtime.h>
#include <stdint.h>

#define KTAPS 8
#define C 32
#define CAP 4   // bucket slots per (out_row, tap) cell; Poisson(0.5): ~600 overflows total

// ---------------------------------------------------------------------------
// init: out[row][c] = bias[c], counts[cell] = 0 (both poisoned 0xAA pre-call)
// ---------------------------------------------------------------------------
__global__ __launch_bounds__(256) void init_kernel(
    float* __restrict__ out, const float* __restrict__ bias,
    unsigned int* __restrict__ counts, int n_out4, int n_cells4) {
  int i = blockIdx.x * 256 + threadIdx.x;
  if (i < n_out4) {
    ((float4*)out)[i] = ((const float4*)bias)[i & 7];
  }
  if (i < n_cells4) {
    ((uint4*)counts)[i] = make_uint4(0u, 0u, 0u, 0u);
  }
}

// ---------------------------------------------------------------------------
// Phase B: one thread per (tap, rule). UNIFORM work: gather input row, do the
// 32x32 GEMM with block-uniform (scalar-loaded) weights at fp32 issue peak,
// write the 128B contribution to a dense stream at deterministic index
// t = k*R + r (no atomic for placement). One int atomic only to claim the
// 4B index slot in the (out_row, tap) bucket. Rare overflow -> direct f32
// atomics on out (correct at any CAP).
// ---------------------------------------------------------------------------
__global__ __launch_bounds__(256) void contrib_kernel(
    const float* __restrict__ in, const float* __restrict__ w,
    const int* __restrict__ rules_in, const int* __restrict__ rules_out,
    float* __restrict__ out, unsigned int* __restrict__ counts,
    unsigned int* __restrict__ bucket_idx, float* __restrict__ contrib,
    int R) {
  const int k = blockIdx.y;
  const int r = blockIdx.x * 256 + threadIdx.x;
  if (r >= R) return;

  const int ri = rules_in[k * R + r];
  const int ro = rules_out[k * R + r];

  // gather input row (128B)
  const float4* rowp = (const float4*)(in + (size_t)ri * C);
  float a[C];
#pragma unroll
  for (int j = 0; j < 8; ++j) {
    float4 v = rowp[j];
    a[4 * j + 0] = v.x; a[4 * j + 1] = v.y;
    a[4 * j + 2] = v.z; a[4 * j + 3] = v.w;
  }

  // 32x32 GEMM, weights via scalar pipe (k is block-uniform)
  const float* wk = w + k * (C * C);
  float acc[C];
#pragma unroll
  for (int co = 0; co < C; ++co) acc[co] = a[0] * wk[co];
#pragma unroll
  for (int ci = 1; ci < C; ++ci)
#pragma unroll
    for (int co = 0; co < C; ++co)
      acc[co] = fmaf(a[ci], wk[ci * C + co], acc[co]);

  // dense stream write at deterministic index
  const unsigned int t = (unsigned int)(k * R + r);
  float4* cp = (float4*)(contrib + (size_t)t * C);
#pragma unroll
  for (int j = 0; j < 8; ++j)
    cp[j] = make_float4(acc[4 * j + 0], acc[4 * j + 1],
                        acc[4 * j + 2], acc[4 * j + 3]);

  // claim index slot
  const unsigned int cell = (unsigned int)ro * KTAPS + (unsigned int)k;
  const unsigned int slot = atomicAdd(counts + cell, 1u);
  if (slot < (unsigned int)CAP) {
    bucket_idx[(size_t)cell * CAP + slot] = t;
  } else {
    float* op = out + (size_t)ro * C;
#pragma unroll
    for (int co = 0; co < C; ++co) unsafeAtomicAdd(op + co, acc[co]);
  }
}

// ---------------------------------------------------------------------------
// Phase C: one thread per output row pulls its ~4 contributions and ADDS them
// (32 adds each — divergence in trip count now costs 32x less than round 2's
// in-loop GEMM). Memory-latency bound. Row written exactly once.
// ---------------------------------------------------------------------------
__global__ __launch_bounds__(256) void reduce_kernel(
    const unsigned int* __restrict__ counts,
    const unsigned int* __restrict__ bucket_idx,
    const float* __restrict__ contrib,
    float* __restrict__ out, int n_out) {
  const int row = blockIdx.x * 256 + threadIdx.x;
  if (row >= n_out) return;

  float acc[C];
  float4* o4 = (float4*)(out + (size_t)row * C);
#pragma unroll
  for (int j = 0; j < 8; ++j) {
    float4 v = o4[j];
    acc[4 * j + 0] = v.x; acc[4 * j + 1] = v.y;
    acc[4 * j + 2] = v.z; acc[4 * j + 3] = v.w;
  }

  // 8 counts for this row in two uint4 loads (cells are row-major)
  const uint4* c4 = (const uint4*)(counts + (size_t)row * KTAPS);
  uint4 c_lo = c4[0], c_hi = c4[1];
  unsigned int cnt[KTAPS] = {c_lo.x, c_lo.y, c_lo.z, c_lo.w,
                             c_hi.x, c_hi.y, c_hi.z, c_hi.w};

  for (int k = 0; k < KTAPS; ++k) {
    unsigned int n = cnt[k];
    if (n > (unsigned int)CAP) n = (unsigned int)CAP;
    const unsigned int* bk = bucket_idx + ((size_t)row * KTAPS + k) * CAP;
    for (unsigned int e = 0; e < n; ++e) {
      const float4* cp = (const float4*)(contrib + (size_t)bk[e] * C);
#pragma unroll
      for (int j = 0; j < 8; ++j) {
        float4 v = cp[j];
        acc[4 * j + 0] += v.x; acc[4 * j + 1] += v.y;
        acc[4 * j + 2] += v.z; acc[4 * j + 3] += v.w;
      }
    }
  }

#pragma unroll
  for (int j = 0; j < 8; ++j)
    o4[j] = make_float4(acc[4 * j + 0], acc[4 * j + 1],
                        acc[4 * j + 2], acc[4 * j + 3]);
}

// ---------------------------------------------------------------------------
// Fallback tier 2 (round-2 kernels, 64 MB ws) and tier 3 (round-1, no ws).
// ---------------------------------------------------------------------------
__global__ __launch_bounds__(256) void bucket_kernel(
    const float* __restrict__ in, const float* __restrict__ w,
    const int* __restrict__ rules_in, const int* __restrict__ rules_out,
    float* __restrict__ out, unsigned int* __restrict__ counts,
    unsigned int* __restrict__ buckets, int R) {
  const int k = blockIdx.y;
  const int r = blockIdx.x * 256 + threadIdx.x;
  if (r >= R) return;
  const int ri = rules_in[k * R + r];
  const int ro = rules_out[k * R + r];
  const unsigned int cell = (unsigned int)ro * KTAPS + (unsigned int)k;
  const unsigned int slot = atomicAdd(counts + cell, 1u);
  if (slot < (unsigned int)CAP) {
    buckets[(size_t)cell * CAP + slot] = (unsigned int)ri;
  } else {
    const float4* rowp = (const float4*)(in + (size_t)ri * C);
    float a[C];
#pragma unroll
    for (int j = 0; j < 8; ++j) {
      float4 v = rowp[j];
      a[4 * j + 0] = v.x; a[4 * j + 1] = v.y;
      a[4 * j + 2] = v.z; a[4 * j + 3] = v.w;
    }
    const float* wk = w + k * (C * C);
    float acc[C];
#pragma unroll
    for (int co = 0; co < C; ++co) acc[co] = a[0] * wk[co];
#pragma unroll
    for (int ci = 1; ci < C; ++ci)
#pragma unroll
      for (int co = 0; co < C; ++co)
        acc[co] = fmaf(a[ci], wk[ci * C + co], acc[co]);
    float* op = out + (size_t)ro * C;
#pragma unroll
    for (int co = 0; co < C; ++co) unsafeAtomicAdd(op + co, acc[co]);
  }
}

__global__ __launch_bounds__(256) void gather_kernel(
    const float* __restrict__ in, const float* __restrict__ w,
    const unsigned int* __restrict__ counts,
    const unsigned int* __restrict__ buckets,
    float* __restrict__ out, int n_out) {
  const int row = blockIdx.x * 256 + threadIdx.x;
  if (row >= n_out) return;
  float acc[C];
  float4* o4 = (float4*)(out + (size_t)row * C);
#pragma unroll
  for (int j = 0; j < 8; ++j) {
    float4 v = o4[j];
    acc[4 * j + 0] = v.x; acc[4 * j + 1] = v.y;
    acc[4 * j + 2] = v.z; acc[4 * j + 3] = v.w;
  }
  for (int k = 0; k < KTAPS; ++k) {
    unsigned int n = counts[(size_t)row * KTAPS + k];
    if (n > (unsigned int)CAP) n = (unsigned int)CAP;
    const float* wk = w + k * (C * C);
    const unsigned int* bk = buckets + ((size_t)row * KTAPS + k) * CAP;
    for (unsigned int e = 0; e < n; ++e) {
      unsigned int ri = bk[e];
      const float4* rowp = (const float4*)(in + (size_t)ri * C);
      float a[C];
#pragma unroll
      for (int j = 0; j < 8; ++j) {
        float4 v = rowp[j];
        a[4 * j + 0] = v.x; a[4 * j + 1] = v.y;
        a[4 * j + 2] = v.z; a[4 * j + 3] = v.w;
      }
#pragma unroll
      for (int ci = 0; ci < C; ++ci)
#pragma unroll
        for (int co = 0; co < C; ++co)
          acc[co] = fmaf(a[ci], wk[ci * C + co], acc[co]);
    }
  }
#pragma unroll
  for (int j = 0; j < 8; ++j)
    o4[j] = make_float4(acc[4 * j + 0], acc[4 * j + 1],
                        acc[4 * j + 2], acc[4 * j + 3]);
}

__global__ __launch_bounds__(256) void bias_init_kernel(
    float* __restrict__ out, const float* __restrict__ bias, int n4) {
  int idx = blockIdx.x * 256 + threadIdx.x;
  if (idx >= n4) return;
  ((float4*)out)[idx] = ((const float4*)bias)[idx & 7];
}

__global__ __launch_bounds__(256) void scatter_gemm_kernel(
    const float* __restrict__ in, const float* __restrict__ w,
    const int* __restrict__ rules_in, const int* __restrict__ rules_out,
    float* __restrict__ out, int R) {
  const int k = blockIdx.y;
  const int r = blockIdx.x * 256 + threadIdx.x;
  if (r >= R) return;
  const int ri = rules_in[k * R + r];
  const int ro = rules_out[k * R + r];
  const float4* rowp = (const float4*)(in + (size_t)ri * C);
  float a[C];
#pragma unroll
  for (int j = 0; j < 8; ++j) {
    float4 v = rowp[j];
    a[4 * j + 0] = v.x; a[4 * j + 1] = v.y;
    a[4 * j + 2] = v.z; a[4 * j + 3] = v.w;
  }
  const float* wk = w + k * (C * C);
  float acc[C];
#pragma unroll
  for (int co = 0; co < C; ++co) acc[co] = a[0] * wk[co];
#pragma unroll
  for (int ci = 1; ci < C; ++ci)
#pragma unroll
    for (int co = 0; co < C; ++co)
      acc[co] = fmaf(a[ci], wk[ci * C + co], acc[co]);
  float* op = out + (size_t)ro * C;
#pragma unroll
  for (int co = 0; co < C; ++co) unsafeAtomicAdd(op + co, acc[co]);
}

extern "C" void kernel_launch(void* const* d_in, const int* in_sizes, int n_in,
                              void* d_out, int out_size, void* d_ws, size_t ws_size,
                              hipStream_t stream) {
  const float* in_features = (const float*)d_in[0];
  const float* weight      = (const float*)d_in[1];
  const float* bias        = (const float*)d_in[2];
  const int*   rules_in    = (const int*)d_in[3];
  const int*   rules_out   = (const int*)d_in[4];

  const int R     = in_sizes[3] / KTAPS;   // 200000
  const int n_out = out_size / C;          // 400000
  float* out = (float*)d_out;

  const size_t n_cells   = (size_t)n_out * KTAPS;                 // 3.2M
  const size_t counts_b  = n_cells * sizeof(unsigned int);        // 12.8 MB
  const size_t bidx_b    = n_cells * CAP * sizeof(unsigned int);  // 51.2 MB
  const size_t n_rules   = (size_t)KTAPS * R;                     // 1.6M
  const size_t contrib_b = n_rules * C * sizeof(float);           // 204.8 MB

  const int n_out4   = out_size / 4;
  const int n_cells4 = (int)(n_cells / 4);
  const int init_n   = n_out4 > n_cells4 ? n_out4 : n_cells4;

  if (ws_size >= counts_b + bidx_b + contrib_b) {
    // ---- Tier 1: dense contribution stream + index buckets ----
    unsigned int* counts  = (unsigned int*)d_ws;
    unsigned int* bidx    = (unsigned int*)((char*)d_ws + counts_b);
    float*        contrib = (float*)((char*)d_ws + counts_b + bidx_b);

    init_kernel<<<(init_n + 255) / 256, 256, 0, stream>>>(out, bias, counts,
                                                          n_out4, n_cells4);
    dim3 gridB((R + 255) / 256, KTAPS);
    contrib_kernel<<<gridB, 256, 0, stream>>>(in_features, weight, rules_in,
                                              rules_out, out, counts, bidx,
                                              contrib, R);
    reduce_kernel<<<(n_out + 255) / 256, 256, 0, stream>>>(counts, bidx,
                                                           contrib, out, n_out);
  } else if (ws_size >= counts_b + bidx_b) {
    // ---- Tier 2: round-2 path ----
    unsigned int* counts  = (unsigned int*)d_ws;
    unsigned int* buckets = (unsigned int*)((char*)d_ws + counts_b);
    init_kernel<<<(init_n + 255) / 256, 256, 0, stream>>>(out, bias, counts,
                                                          n_out4, n_cells4);
    dim3 gridB((R + 255) / 256, KTAPS);
    bucket_kernel<<<gridB, 256, 0, stream>>>(in_features, weight, rules_in,
                                             rules_out, out, counts, buckets, R);
    gather_kernel<<<(n_out + 255) / 256, 256, 0, stream>>>(
        in_features, weight, counts, buckets, out, n_out);
  } else {
    // ---- Tier 3: round-1 path ----
    bias_init_kernel<<<(n_out4 + 255) / 256, 256, 0, stream>>>(out, bias, n_out4);
    dim3 grid((R + 255) / 256, KTAPS);
    scatter_gemm_kernel<<<grid, 256, 0, stream>>>(in_features, weight, rules_in,
                                                  rules_out, out, R);
  }
}